// Round 6
// baseline (157.661 us; speedup 1.0000x reference)
//
#include <hip/hip_runtime.h>

// EdgeLoss: mean |sobel_mag(gray(pred)) - sobel_mag(gray(target))|
// Inputs: prediction [16,3,512,512] f32, target [16,3,512,512] f32. Output: scalar f32.
// R6: __launch_bounds__(256,8) -> VGPR cap 64 (usage 48), targets 32 waves/CU
// (LDS 19.9KB allows exactly 8 blocks/CU). More resident waves = more loads
// in flight = higher sustained HBM BW. Stage-1 stores partials (no atomics);
// stage-2 reduces 2048 floats.

constexpr int B = 16;
constexpr int H = 512;
constexpr int W = 512;
constexpr int TH = 32;             // output rows per block
constexpr int TW = 64;             // output cols per block
constexpr int HROWS = TH + 2;      // 34 halo rows
constexpr int LSTRIDE = 72;        // LDS row stride (floats); center cols [4..67], 16B aligned
constexpr int NTHREADS = 256;
constexpr int TILES_W = W / TW;            // 8
constexpr int TILES_H = H / TH;            // 16
constexpr int TILES_PER_IMG = TILES_W * TILES_H;   // 128
constexpr int NBLOCKS = B * TILES_PER_IMG;         // 2048
constexpr float EPS = 1e-6f;

__device__ __forceinline__ float4 ldg4(const float* p) {
    return *reinterpret_cast<const float4*>(p);
}

__device__ __forceinline__ float4 gray4(float4 r, float4 g, float4 b) {
    float4 o;
    o.x = 0.299f * r.x + 0.587f * g.x + 0.114f * b.x;
    o.y = 0.299f * r.y + 0.587f * g.y + 0.114f * b.y;
    o.z = 0.299f * r.z + 0.587f * g.z + 0.114f * b.z;
    o.w = 0.299f * r.w + 0.587f * g.w + 0.114f * b.w;
    return o;
}

// 8 waves/EU = 32 waves/CU target; VGPR cap 64 (current usage 48, no spill).
__global__ __launch_bounds__(NTHREADS, 8) void edge_loss_kernel(
    const float* __restrict__ pred,
    const float* __restrict__ targ,
    float* __restrict__ partial)
{
    __shared__ alignas(16) float sp[HROWS][LSTRIDE];
    __shared__ alignas(16) float st[HROWS][LSTRIDE];

    const int bid = blockIdx.x;
    const int b   = bid / TILES_PER_IMG;
    const int t   = bid % TILES_PER_IMG;
    const int th0 = (t / TILES_W) * TH;
    const int tw0 = (t % TILES_W) * TW;
    const int tid = threadIdx.x;
    const size_t plane = (size_t)H * W;

    const float* __restrict__ p0 = pred + (size_t)b * 3 * plane;
    const float* __restrict__ p1 = p0 + plane;
    const float* __restrict__ p2 = p0 + 2 * plane;
    const float* __restrict__ t0 = targ + (size_t)b * 3 * plane;
    const float* __restrict__ t1 = t0 + plane;
    const float* __restrict__ t2 = t0 + 2 * plane;

    // staging task g -> (row, k): row = g>>4 (0..33), k = g&15 (float4 col group)
    // NGRP = 34*16 = 544 = 256 (A) + 256 (B) + 32 (C, tid<32)
    const int rowA = tid >> 4, kA = tid & 15;
    const int gB = tid + 256;
    const int rowB = gB >> 4, kB = gB & 15;
    const int offA = (min(max(th0 - 1 + rowA, 0), H - 1)) * W + tw0 + 4 * kA;
    const int offB = (min(max(th0 - 1 + rowB, 0), H - 1)) * W + tw0 + 4 * kB;

    // ---- issue ALL loads before ANY consume ----
    const float4 Apr = ldg4(p0 + offA), Apg = ldg4(p1 + offA), Apb = ldg4(p2 + offA);
    const float4 Atr = ldg4(t0 + offA), Atg = ldg4(t1 + offA), Atb = ldg4(t2 + offA);
    const float4 Bpr = ldg4(p0 + offB), Bpg = ldg4(p1 + offB), Bpb = ldg4(p2 + offB);
    const float4 Btr = ldg4(t0 + offB), Btg = ldg4(t1 + offB), Btb = ldg4(t2 + offB);

    // halo edge columns (tid<136): 3 scalar loads
    float hv0 = 0.f, hv1 = 0.f, hv2 = 0.f;
    int hrow = 0, hside = 0, himg = 0;
    if (tid < 4 * HROWS) {
        himg = tid & 1;
        const int rr = tid >> 1;           // 0..67
        hside = rr >= HROWS;
        hrow  = hside ? rr - HROWS : rr;
        const int grow = min(max(th0 - 1 + hrow, 0), H - 1);
        const int gcol = hside ? min(tw0 + TW, W - 1) : max(tw0 - 1, 0);
        const float* ip = (himg ? t0 : p0) + (size_t)grow * W + gcol;
        hv0 = ip[0]; hv1 = ip[plane]; hv2 = ip[2 * plane];
    }

    // group C (rows 32..33, tid<32)
    float4 Cpr, Cpg, Cpb, Ctr, Ctg, Ctb;
    int rowC = 0, kC = 0;
    if (tid < 32) {
        const int gC = tid + 512;
        rowC = gC >> 4; kC = gC & 15;
        const int offC = (min(max(th0 - 1 + rowC, 0), H - 1)) * W + tw0 + 4 * kC;
        Cpr = ldg4(p0 + offC); Cpg = ldg4(p1 + offC); Cpb = ldg4(p2 + offC);
        Ctr = ldg4(t0 + offC); Ctg = ldg4(t1 + offC); Ctb = ldg4(t2 + offC);
    }

    // ---- consume (in issue order; vmcnt drains progressively) ----
    *reinterpret_cast<float4*>(&sp[rowA][4 + 4 * kA]) = gray4(Apr, Apg, Apb);
    *reinterpret_cast<float4*>(&st[rowA][4 + 4 * kA]) = gray4(Atr, Atg, Atb);
    *reinterpret_cast<float4*>(&sp[rowB][4 + 4 * kB]) = gray4(Bpr, Bpg, Bpb);
    *reinterpret_cast<float4*>(&st[rowB][4 + 4 * kB]) = gray4(Btr, Btg, Btb);

    if (tid < 4 * HROWS) {
        const float v = 0.299f * hv0 + 0.587f * hv1 + 0.114f * hv2;
        float (*dst)[LSTRIDE] = himg ? st : sp;
        dst[hrow][hside ? 68 : 3] = v;
    }
    if (tid < 32) {
        *reinterpret_cast<float4*>(&sp[rowC][4 + 4 * kC]) = gray4(Cpr, Cpg, Cpb);
        *reinterpret_cast<float4*>(&st[rowC][4 + 4 * kC]) = gray4(Ctr, Ctg, Ctb);
    }

    __syncthreads();

    // ---- Compute: vertical rolling 3x3 window, 8 rows per thread ----
    const int lw = tid & 63;               // column within tile
    const int q  = tid >> 6;               // wave index = vertical quarter
    const int r0 = q * 8;                  // top halo row for this strip
    const int c0 = lw + 3, c1 = lw + 4, c2 = lw + 5;

    float pa0 = sp[r0][c0],     pa1 = sp[r0][c1],     pa2 = sp[r0][c2];
    float pb0 = sp[r0 + 1][c0], pb1 = sp[r0 + 1][c1], pb2 = sp[r0 + 1][c2];
    float ta0 = st[r0][c0],     ta1 = st[r0][c1],     ta2 = st[r0][c2];
    float tb0 = st[r0 + 1][c0], tb1 = st[r0 + 1][c1], tb2 = st[r0 + 1][c2];

    float acc = 0.0f;
    #pragma unroll
    for (int r = 0; r < 8; ++r) {
        const int hr = r0 + r + 2;
        const float pc0 = sp[hr][c0], pc1 = sp[hr][c1], pc2 = sp[hr][c2];
        const float tc0 = st[hr][c0], tc1 = st[hr][c1], tc2 = st[hr][c2];

        float gx = ((pa2 - pa0) + 2.0f * (pb2 - pb0) + (pc2 - pc0)) * 0.125f;
        float gy = ((pc0 - pa0) + 2.0f * (pc1 - pa1) + (pc2 - pa2)) * 0.125f;
        const float pe = sqrtf(gx * gx + gy * gy + EPS);

        float hx = ((ta2 - ta0) + 2.0f * (tb2 - tb0) + (tc2 - tc0)) * 0.125f;
        float hy = ((tc0 - ta0) + 2.0f * (tc1 - ta1) + (tc2 - ta2)) * 0.125f;
        const float te = sqrtf(hx * hx + hy * hy + EPS);

        acc += fabsf(pe - te);

        pa0 = pb0; pa1 = pb1; pa2 = pb2;
        pb0 = pc0; pb1 = pc1; pb2 = pc2;
        ta0 = tb0; ta1 = tb1; ta2 = tb2;
        tb0 = tc0; tb1 = tc1; tb2 = tc2;
    }

    // ---- Block reduction -> one plain store per block (no atomics) ----
    #pragma unroll
    for (int off = 32; off > 0; off >>= 1)
        acc += __shfl_down(acc, off);

    __shared__ float wsum[NTHREADS / 64];
    if ((tid & 63) == 0) wsum[tid >> 6] = acc;
    __syncthreads();

    if (tid == 0) {
        partial[bid] = wsum[0] + wsum[1] + wsum[2] + wsum[3];
    }
}

__global__ __launch_bounds__(256) void reduce_kernel(
    const float* __restrict__ partial,
    float* __restrict__ out)
{
    const int tid = threadIdx.x;
    float acc = 0.0f;
    #pragma unroll
    for (int i = 0; i < NBLOCKS / 256; ++i)      // 8 coalesced loads
        acc += partial[tid + i * 256];

    #pragma unroll
    for (int off = 32; off > 0; off >>= 1)
        acc += __shfl_down(acc, off);

    __shared__ float wsum[4];
    if ((tid & 63) == 0) wsum[tid >> 6] = acc;
    __syncthreads();

    if (tid == 0) {
        const float s = wsum[0] + wsum[1] + wsum[2] + wsum[3];
        out[0] = s * (1.0f / (float)((size_t)B * H * W));  // 2^-22, exact
    }
}

extern "C" void kernel_launch(void* const* d_in, const int* in_sizes, int n_in,
                              void* d_out, int out_size, void* d_ws, size_t ws_size,
                              hipStream_t stream) {
    const float* pred = (const float*)d_in[0];
    const float* targ = (const float*)d_in[1];
    float* out = (float*)d_out;
    float* partial = (float*)d_ws;           // 2048 floats = 8 KB scratch

    edge_loss_kernel<<<NBLOCKS, NTHREADS, 0, stream>>>(pred, targ, partial);
    reduce_kernel<<<1, 256, 0, stream>>>(partial, out);
}

// Round 7
// 124.918 us; speedup vs baseline: 1.2621x; 1.2621x over previous
//
#include <hip/hip_runtime.h>

// EdgeLoss: mean |sobel_mag(gray(pred)) - sobel_mag(gray(target))|
// Inputs: prediction [16,3,512,512] f32, target [16,3,512,512] f32. Output: scalar f32.
// R7: two-tile software pipeline. Each block does a vertical 32x64 tile PAIR:
// tile1's global loads are issued (into regs) before tile0's compute, so the
// HBM drain of tile1 overlaps tile0's LDS/VALU phase (T14 async-STAGE split).
// lb(256,4): VGPR cap 128 (R6 showed cap 64 -> spills; R4 showed 48 used for
// one tile in flight; two tiles need ~100-120).

constexpr int B = 16;
constexpr int H = 512;
constexpr int W = 512;
constexpr int TH = 32;             // output rows per tile
constexpr int TW = 64;             // output cols per tile
constexpr int HROWS = TH + 2;      // 34 halo rows
constexpr int LSTRIDE = 72;        // LDS row stride (floats); center cols [4..67], 16B aligned
constexpr int NTHREADS = 256;
constexpr int PAIRS_W = W / TW;             // 8
constexpr int PAIRS_H = H / (2 * TH);       // 8 (pair = 64 rows)
constexpr int PAIRS_PER_IMG = PAIRS_W * PAIRS_H;   // 64
constexpr int NBLOCKS = B * PAIRS_PER_IMG;         // 1024
constexpr float EPS = 1e-6f;

__device__ __forceinline__ float4 ldg4(const float* p) {
    return *reinterpret_cast<const float4*>(p);
}

__device__ __forceinline__ float4 gray4(float4 r, float4 g, float4 b) {
    float4 o;
    o.x = 0.299f * r.x + 0.587f * g.x + 0.114f * b.x;
    o.y = 0.299f * r.y + 0.587f * g.y + 0.114f * b.y;
    o.z = 0.299f * r.z + 0.587f * g.z + 0.114f * b.z;
    o.w = 0.299f * r.w + 0.587f * g.w + 0.114f * b.w;
    return o;
}

// All in-flight loads for one 34x66 grayscale tile (both images).
struct Stage {
    float4 Apr, Apg, Apb, Atr, Atg, Atb;   // rows 0..15
    float4 Bpr, Bpg, Bpb, Btr, Btg, Btb;   // rows 16..31
    float  hv0, hv1, hv2;                  // halo edge cols (tid<136)
    float4 Cpr, Cpg, Cpb, Ctr, Ctg, Ctb;   // rows 32..33 (tid<32)
};

__device__ __forceinline__ Stage issue_stage(
    const float* __restrict__ p0, const float* __restrict__ p1, const float* __restrict__ p2,
    const float* __restrict__ t0, const float* __restrict__ t1, const float* __restrict__ t2,
    int th0, int tw0, int tid, size_t plane)
{
    Stage S;
    S.hv0 = S.hv1 = S.hv2 = 0.0f;

    const int rowA = tid >> 4, kA = tid & 15;
    const int gB = tid + 256;
    const int rowB = gB >> 4, kB = gB & 15;
    const int offA = (min(max(th0 - 1 + rowA, 0), H - 1)) * W + tw0 + 4 * kA;
    const int offB = (min(max(th0 - 1 + rowB, 0), H - 1)) * W + tw0 + 4 * kB;

    S.Apr = ldg4(p0 + offA); S.Apg = ldg4(p1 + offA); S.Apb = ldg4(p2 + offA);
    S.Atr = ldg4(t0 + offA); S.Atg = ldg4(t1 + offA); S.Atb = ldg4(t2 + offA);
    S.Bpr = ldg4(p0 + offB); S.Bpg = ldg4(p1 + offB); S.Bpb = ldg4(p2 + offB);
    S.Btr = ldg4(t0 + offB); S.Btg = ldg4(t1 + offB); S.Btb = ldg4(t2 + offB);

    if (tid < 4 * HROWS) {                  // 136 halo-column tasks
        const int img  = tid & 1;
        const int rr   = tid >> 1;          // 0..67
        const int side = rr >= HROWS;
        const int row  = side ? rr - HROWS : rr;
        const int grow = min(max(th0 - 1 + row, 0), H - 1);
        const int gcol = side ? min(tw0 + TW, W - 1) : max(tw0 - 1, 0);
        const float* ip = (img ? t0 : p0) + (size_t)grow * W + gcol;
        S.hv0 = ip[0]; S.hv1 = ip[plane]; S.hv2 = ip[2 * plane];
    }
    if (tid < 32) {                         // rows 32..33
        const int gC = tid + 512;
        const int rowC = gC >> 4, kC = gC & 15;
        const int offC = (min(max(th0 - 1 + rowC, 0), H - 1)) * W + tw0 + 4 * kC;
        S.Cpr = ldg4(p0 + offC); S.Cpg = ldg4(p1 + offC); S.Cpb = ldg4(p2 + offC);
        S.Ctr = ldg4(t0 + offC); S.Ctg = ldg4(t1 + offC); S.Ctb = ldg4(t2 + offC);
    }
    return S;
}

__device__ __forceinline__ void consume_stage(
    const Stage& S, float sp[HROWS][LSTRIDE], float st[HROWS][LSTRIDE], int tid)
{
    const int rowA = tid >> 4, kA = tid & 15;
    const int gB = tid + 256;
    const int rowB = gB >> 4, kB = gB & 15;

    *reinterpret_cast<float4*>(&sp[rowA][4 + 4 * kA]) = gray4(S.Apr, S.Apg, S.Apb);
    *reinterpret_cast<float4*>(&st[rowA][4 + 4 * kA]) = gray4(S.Atr, S.Atg, S.Atb);
    *reinterpret_cast<float4*>(&sp[rowB][4 + 4 * kB]) = gray4(S.Bpr, S.Bpg, S.Bpb);
    *reinterpret_cast<float4*>(&st[rowB][4 + 4 * kB]) = gray4(S.Btr, S.Btg, S.Btb);

    if (tid < 4 * HROWS) {
        const int img  = tid & 1;
        const int rr   = tid >> 1;
        const int side = rr >= HROWS;
        const int row  = side ? rr - HROWS : rr;
        const float v = 0.299f * S.hv0 + 0.587f * S.hv1 + 0.114f * S.hv2;
        float (*dst)[LSTRIDE] = img ? st : sp;
        dst[row][side ? 68 : 3] = v;
    }
    if (tid < 32) {
        const int gC = tid + 512;
        const int rowC = gC >> 4, kC = gC & 15;
        *reinterpret_cast<float4*>(&sp[rowC][4 + 4 * kC]) = gray4(S.Cpr, S.Cpg, S.Cpb);
        *reinterpret_cast<float4*>(&st[rowC][4 + 4 * kC]) = gray4(S.Ctr, S.Ctg, S.Ctb);
    }
}

__device__ __forceinline__ float compute_tile(
    const float sp[HROWS][LSTRIDE], const float st[HROWS][LSTRIDE], int tid)
{
    const int lw = tid & 63;
    const int q  = tid >> 6;
    const int r0 = q * 8;
    const int c0 = lw + 3, c1 = lw + 4, c2 = lw + 5;

    float pa0 = sp[r0][c0],     pa1 = sp[r0][c1],     pa2 = sp[r0][c2];
    float pb0 = sp[r0 + 1][c0], pb1 = sp[r0 + 1][c1], pb2 = sp[r0 + 1][c2];
    float ta0 = st[r0][c0],     ta1 = st[r0][c1],     ta2 = st[r0][c2];
    float tb0 = st[r0 + 1][c0], tb1 = st[r0 + 1][c1], tb2 = st[r0 + 1][c2];

    float acc = 0.0f;
    #pragma unroll
    for (int r = 0; r < 8; ++r) {
        const int hr = r0 + r + 2;
        const float pc0 = sp[hr][c0], pc1 = sp[hr][c1], pc2 = sp[hr][c2];
        const float tc0 = st[hr][c0], tc1 = st[hr][c1], tc2 = st[hr][c2];

        float gx = ((pa2 - pa0) + 2.0f * (pb2 - pb0) + (pc2 - pc0)) * 0.125f;
        float gy = ((pc0 - pa0) + 2.0f * (pc1 - pa1) + (pc2 - pa2)) * 0.125f;
        const float pe = sqrtf(gx * gx + gy * gy + EPS);

        float hx = ((ta2 - ta0) + 2.0f * (tb2 - tb0) + (tc2 - tc0)) * 0.125f;
        float hy = ((tc0 - ta0) + 2.0f * (tc1 - ta1) + (tc2 - ta2)) * 0.125f;
        const float te = sqrtf(hx * hx + hy * hy + EPS);

        acc += fabsf(pe - te);

        pa0 = pb0; pa1 = pb1; pa2 = pb2;
        pb0 = pc0; pb1 = pc1; pb2 = pc2;
        ta0 = tb0; ta1 = tb1; ta2 = tb2;
        tb0 = tc0; tb1 = tc1; tb2 = tc2;
    }
    return acc;
}

__global__ __launch_bounds__(NTHREADS, 4) void edge_loss_kernel(
    const float* __restrict__ pred,
    const float* __restrict__ targ,
    float* __restrict__ partial)
{
    __shared__ alignas(16) float sp[HROWS][LSTRIDE];
    __shared__ alignas(16) float st[HROWS][LSTRIDE];

    const int bid = blockIdx.x;
    const int b   = bid / PAIRS_PER_IMG;
    const int t   = bid % PAIRS_PER_IMG;
    const int th0 = (t / PAIRS_W) * (2 * TH);   // top row of the pair
    const int tw0 = (t % PAIRS_W) * TW;
    const int tid = threadIdx.x;
    const size_t plane = (size_t)H * W;

    const float* __restrict__ p0 = pred + (size_t)b * 3 * plane;
    const float* __restrict__ p1 = p0 + plane;
    const float* __restrict__ p2 = p0 + 2 * plane;
    const float* __restrict__ t0 = targ + (size_t)b * 3 * plane;
    const float* __restrict__ t1 = t0 + plane;
    const float* __restrict__ t2 = t0 + 2 * plane;

    // ---- tile 0: issue + consume ----
    Stage S0 = issue_stage(p0, p1, p2, t0, t1, t2, th0, tw0, tid, plane);
    consume_stage(S0, sp, st, tid);
    __syncthreads();

    // ---- tile 1: issue loads NOW (drain overlaps tile-0 compute) ----
    Stage S1 = issue_stage(p0, p1, p2, t0, t1, t2, th0 + TH, tw0, tid, plane);

    float acc = compute_tile(sp, st, tid);
    __syncthreads();                    // everyone done reading LDS tile 0

    consume_stage(S1, sp, st, tid);
    __syncthreads();

    acc += compute_tile(sp, st, tid);

    // ---- block reduction -> one plain store per block (no atomics) ----
    #pragma unroll
    for (int off = 32; off > 0; off >>= 1)
        acc += __shfl_down(acc, off);

    __shared__ float wsum[NTHREADS / 64];
    if ((tid & 63) == 0) wsum[tid >> 6] = acc;
    __syncthreads();

    if (tid == 0) {
        partial[bid] = wsum[0] + wsum[1] + wsum[2] + wsum[3];
    }
}

__global__ __launch_bounds__(256) void reduce_kernel(
    const float* __restrict__ partial,
    float* __restrict__ out)
{
    const int tid = threadIdx.x;
    float acc = 0.0f;
    #pragma unroll
    for (int i = 0; i < NBLOCKS / 256; ++i)      // 4 coalesced loads
        acc += partial[tid + i * 256];

    #pragma unroll
    for (int off = 32; off > 0; off >>= 1)
        acc += __shfl_down(acc, off);

    __shared__ float wsum[4];
    if ((tid & 63) == 0) wsum[tid >> 6] = acc;
    __syncthreads();

    if (tid == 0) {
        const float s = wsum[0] + wsum[1] + wsum[2] + wsum[3];
        out[0] = s * (1.0f / (float)((size_t)B * H * W));  // 2^-22, exact
    }
}

extern "C" void kernel_launch(void* const* d_in, const int* in_sizes, int n_in,
                              void* d_out, int out_size, void* d_ws, size_t ws_size,
                              hipStream_t stream) {
    const float* pred = (const float*)d_in[0];
    const float* targ = (const float*)d_in[1];
    float* out = (float*)d_out;
    float* partial = (float*)d_ws;           // 1024 floats = 4 KB scratch

    edge_loss_kernel<<<NBLOCKS, NTHREADS, 0, stream>>>(pred, targ, partial);
    reduce_kernel<<<1, 256, 0, stream>>>(partial, out);
}